// Round 10
// baseline (224.056 us; speedup 1.0000x reference)
//
#include <hip/hip_runtime.h>
#include <hip/hip_cooperative_groups.h>

namespace cg = cooperative_groups;

// SelfAttention2d, B=8 C=256 H=W=64 (N=4096), Ck=32, softmax dead code.
// out = gamma * (v q^T k) + x, reassociated:
//   Qt = X^T Wq^T + 1 bq^T      (N x 32, per-tile, LDS only)
//   Kt_t = X^T Wk^T             (N x 32, bf16, ws; bk folded into h)
//   T  = X Qt                   (256 x 32) n-chunked partials -> ws
//   qsum = Qt^T 1               (32)
//   P  = Wv T + bv qsum^T       (256 x 32), h = P bk  (j-split)
//   out = gamma * (P Kt + h 1^T) + x
// R10: all phases fused into ONE cooperative kernel (512 blocks = 2/CU
// exactly co-resident; 77.8 KB LDS; launch_bounds(256,2)) with grid.sync()
// between phases. Bodies are R7-exact (pgemm 16-row load fixed). Fallback
// to the R7 4-dispatch path if cooperative launch is rejected.

constexpr int NB = 8;
constexpr int NC = 256;
constexpr int NK = 32;     // C/8
constexpr int NN = 4096;   // H*W
constexpr int NCHUNK = 64; // front n-chunks (64 n each)

typedef float  f32x4  __attribute__((ext_vector_type(4)));
typedef __bf16 bf16x4 __attribute__((ext_vector_type(4)));
typedef __bf16 bf16x8 __attribute__((ext_vector_type(8)));

__device__ __forceinline__ bf16x8 load_bf8(const float* __restrict__ p) {
  f32x4 a = *(const f32x4*)p;
  f32x4 b = *(const f32x4*)(p + 4);
  bf16x8 r;
  r[0] = (__bf16)a[0]; r[1] = (__bf16)a[1]; r[2] = (__bf16)a[2]; r[3] = (__bf16)a[3];
  r[4] = (__bf16)b[0]; r[5] = (__bf16)b[1]; r[6] = (__bf16)b[2]; r[7] = (__bf16)b[3];
  return r;
}

struct SmemFront {
  __bf16 ldsT[64 * 264];   // x-subtile transposed [n][c], XOR-swizzled
  __bf16 ldsW[2][32][264]; // Wq, Wk bf16 [j][c]
  __bf16 ldsQt[32][72];    // Q^T subtile [j][n]
  __bf16 ldsKt[32][72];    // K^T subtile [j][n]
  float  ldsQs[4][32];
};
struct SmemP {
  __bf16 shTt[16][264];    // T^T half [j][c]
  float  shQsum[16];
};
union SmemU { SmemFront f; SmemP p; };

// ---------------- phase 1: front (R7 exact) ----------------------------------
__device__ __forceinline__ void front_body(
    SmemFront& s, const float* __restrict__ x, const float* __restrict__ Wq,
    const float* __restrict__ bq, const float* __restrict__ Wk,
    __bf16* __restrict__ Tpart, __bf16* __restrict__ Kt_t,
    float* __restrict__ qsum_part, int bid, int t) {
  int b = bid >> 6, chunk = bid & 63;
  int nsub = chunk * 64;
  int lane = t & 63, w = t >> 6, lr = lane & 15, lg = lane >> 4;
  const float* xb = x + (size_t)b * NC * NN;
  float bq0 = bq[lr], bq1 = bq[16 + lr];

  {  // weight stage: Wq/Wk f32[32][256] -> ldsW bf16, once per block
    int m = t >> 7, tid = t & 127;
    int j = tid >> 2, c0 = (tid & 3) * 64;
    const float* Ws = m ? Wk : Wq;
#pragma unroll
    for (int i = 0; i < 16; ++i) {
      f32x4 v = *(const f32x4*)(Ws + j * NC + c0 + i * 4);
      bf16x4 pk = {(__bf16)v[0], (__bf16)v[1], (__bf16)v[2], (__bf16)v[3]};
      *(bf16x4*)&s.ldsW[m][j][c0 + i * 4] = pk;
    }
  }
  {  // stage x[0:256][nsub:nsub+64] -> ldsT swizzled, fully coalesced reads
    int cg_ = t >> 4, ng = t & 15;
    int n0 = ng * 4;
    int swzEl = (ng & 7) << 3;
#pragma unroll
    for (int r = 0; r < 4; ++r) {
      int c0 = r * 64 + cg_ * 4;
      const float* src = xb + (size_t)c0 * NN + nsub + n0;
      f32x4 L0 = *(const f32x4*)(src);
      f32x4 L1 = *(const f32x4*)(src + NN);
      f32x4 L2 = *(const f32x4*)(src + 2 * NN);
      f32x4 L3 = *(const f32x4*)(src + 3 * NN);
#pragma unroll
      for (int jj = 0; jj < 4; ++jj) {
        bf16x4 pk = {(__bf16)L0[jj], (__bf16)L1[jj], (__bf16)L2[jj], (__bf16)L3[jj]};
        *(bf16x4*)&s.ldsT[(n0 + jj) * 264 + (c0 ^ swzEl)] = pk;
      }
    }
  }
  __syncthreads();
  // Qt(64x32) and Kt(64x32): all-LDS operands; A-frag reads use the swizzle
  f32x4 aq[2] = {}, ak[2] = {};
  {
    int n = w * 16 + lr;
    int swzA = ((n >> 2) & 7) << 3;
    int rowA = n * 264;
#pragma unroll
    for (int ks = 0; ks < 8; ++ks) {
      bf16x8 af = *(const bf16x8*)&s.ldsT[rowA + ((ks * 32 + lg * 8) ^ swzA)];
      bf16x8 q0 = *(const bf16x8*)&s.ldsW[0][lr][ks * 32 + lg * 8];
      bf16x8 q1 = *(const bf16x8*)&s.ldsW[0][16 + lr][ks * 32 + lg * 8];
      bf16x8 k0 = *(const bf16x8*)&s.ldsW[1][lr][ks * 32 + lg * 8];
      bf16x8 k1 = *(const bf16x8*)&s.ldsW[1][16 + lr][ks * 32 + lg * 8];
      aq[0] = __builtin_amdgcn_mfma_f32_16x16x32_bf16(af, q0, aq[0], 0, 0, 0);
      aq[1] = __builtin_amdgcn_mfma_f32_16x16x32_bf16(af, q1, aq[1], 0, 0, 0);
      ak[0] = __builtin_amdgcn_mfma_f32_16x16x32_bf16(af, k0, ak[0], 0, 0, 0);
      ak[1] = __builtin_amdgcn_mfma_f32_16x16x32_bf16(af, k1, ak[1], 0, 0, 0);
    }
  }
  float qs0, qs1;
#pragma unroll
  for (int r = 0; r < 4; ++r) { aq[0][r] += bq0; aq[1][r] += bq1; }
  qs0 = aq[0][0] + aq[0][1] + aq[0][2] + aq[0][3];
  qs1 = aq[1][0] + aq[1][1] + aq[1][2] + aq[1][3];
  {  // Qt / Kt -> LDS [j][n]
    bf16x4 p0 = {(__bf16)aq[0][0], (__bf16)aq[0][1], (__bf16)aq[0][2], (__bf16)aq[0][3]};
    bf16x4 p1 = {(__bf16)aq[1][0], (__bf16)aq[1][1], (__bf16)aq[1][2], (__bf16)aq[1][3]};
    *(bf16x4*)&s.ldsQt[lr][w * 16 + lg * 4] = p0;
    *(bf16x4*)&s.ldsQt[16 + lr][w * 16 + lg * 4] = p1;
    bf16x4 k0p = {(__bf16)ak[0][0], (__bf16)ak[0][1], (__bf16)ak[0][2], (__bf16)ak[0][3]};
    bf16x4 k1p = {(__bf16)ak[1][0], (__bf16)ak[1][1], (__bf16)ak[1][2], (__bf16)ak[1][3]};
    *(bf16x4*)&s.ldsKt[lr][w * 16 + lg * 4] = k0p;
    *(bf16x4*)&s.ldsKt[16 + lr][w * 16 + lg * 4] = k1p;
  }
  __syncthreads();
  {  // Kt coalesced store: thread t covers (nloc = t>>2, 8 j) -> 16 B store
    int nloc = t >> 2, j0 = (t & 3) * 8;
    bf16x8 pk;
#pragma unroll
    for (int i = 0; i < 8; ++i) pk[i] = s.ldsKt[j0 + i][nloc];
    *(bf16x8*)&Kt_t[((size_t)b * NN + nsub + nloc) * NK + j0] = pk;
  }
  // T(256x32) = X Qt : A = x rows from global (L1/L2-hot), B = ldsQt rows
  f32x4 accT[4][2] = {};
#pragma unroll
  for (int ks2 = 0; ks2 < 2; ++ks2) {
    bf16x8 bf0 = *(const bf16x8*)&s.ldsQt[lr][ks2 * 32 + lg * 8];
    bf16x8 bf1 = *(const bf16x8*)&s.ldsQt[16 + lr][ks2 * 32 + lg * 8];
#pragma unroll
    for (int mt = 0; mt < 4; ++mt) {
      int c = w * 64 + mt * 16 + lr;
      bf16x8 af = load_bf8(xb + (size_t)c * NN + nsub + ks2 * 32 + lg * 8);
      accT[mt][0] = __builtin_amdgcn_mfma_f32_16x16x32_bf16(af, bf0, accT[mt][0], 0, 0, 0);
      accT[mt][1] = __builtin_amdgcn_mfma_f32_16x16x32_bf16(af, bf1, accT[mt][1], 0, 0, 0);
    }
  }
  // qsum partial
  qs0 += __shfl_xor(qs0, 16); qs0 += __shfl_xor(qs0, 32);
  qs1 += __shfl_xor(qs1, 16); qs1 += __shfl_xor(qs1, 32);
  if (lane < 16) { s.ldsQs[w][lane] = qs0; s.ldsQs[w][16 + lane] = qs1; }
  __syncthreads();
  if (t < 32)
    qsum_part[(size_t)(chunk * NB + b) * NK + t] =
        s.ldsQs[0][t] + s.ldsQs[1][t] + s.ldsQs[2][t] + s.ldsQs[3][t];
  // Tpart[chunk][b][j][c] bf16
  __bf16* Tp = Tpart + (size_t)(chunk * NB + b) * NC * NK;
#pragma unroll
  for (int mt = 0; mt < 4; ++mt)
#pragma unroll
    for (int jf = 0; jf < 2; ++jf) {
      bf16x4 pk = {(__bf16)accT[mt][jf][0], (__bf16)accT[mt][jf][1],
                   (__bf16)accT[mt][jf][2], (__bf16)accT[mt][jf][3]};
      *(bf16x4*)&Tp[(jf * 16 + lr) * NC + w * 64 + mt * 16 + lg * 4] = pk;
    }
}

// ---------------- phase 2a: reduce (R7 exact; blocks 0-63) -------------------
__device__ __forceinline__ void reduce_body(__bf16* __restrict__ Tpart,
                                            int bid, int t) {
  int b = bid >> 3, slice = bid & 7;
  int jo = t >> 6, c0 = (t & 63) * 4;
  const size_t chstride = (size_t)NB * NK * NC;
  size_t idx = ((size_t)b * NK + slice * 4 + jo) * NC + c0;
  float acc[4] = {};
#pragma unroll 8
  for (int ch = 0; ch < NCHUNK; ++ch) {
    bf16x4 v = *(const bf16x4*)&Tpart[ch * chstride + idx];
#pragma unroll
    for (int i = 0; i < 4; ++i) acc[i] += (float)v[i];
  }
  bf16x4 o = {(__bf16)acc[0], (__bf16)acc[1], (__bf16)acc[2], (__bf16)acc[3]};
  *(bf16x4*)&Tpart[idx] = o;
}

// ---------------- phase 2b: pgemm (blocks 0-15; 16-row load FIXED) -----------
__device__ __forceinline__ void pgemm_body(
    SmemP& s, const __bf16* __restrict__ T, const float* __restrict__ qsum_part,
    const float* __restrict__ Wv, const float* __restrict__ bv,
    const float* __restrict__ bk, __bf16* __restrict__ P,
    float* __restrict__ h2, int bid, int t) {
  int b = bid >> 1, jg = bid & 1;
  if (t < 16) {
    float sq = 0.f;
#pragma unroll 8
    for (int ch = 0; ch < NCHUNK; ++ch)
      sq += qsum_part[(size_t)(ch * NB + b) * NK + jg * 16 + t];
    s.shQsum[t] = sq;
  }
  {  // copy reduced T half (16j x 256c bf16 = 8 KB) into LDS — all 16 rows
    int j = t >> 4, c0 = (t & 15) * 16;
    const __bf16* src = &T[((size_t)b * NK + jg * 16 + j) * NC + c0];
    bf16x8 v0 = *(const bf16x8*)src;
    bf16x8 v1 = *(const bf16x8*)(src + 8);
    *(bf16x8*)&s.shTt[j][c0] = v0;
    *(bf16x8*)&s.shTt[j][c0 + 8] = v1;
  }
  __syncthreads();
  int lane = t & 63, w = t >> 6, lr = lane & 15, lg = lane >> 4;
  float bkj = bk[jg * 16 + lr];
  f32x4 accP[4] = {};
#pragma unroll
  for (int ks = 0; ks < 8; ++ks) {
    bf16x8 b0 = *(const bf16x8*)&s.shTt[lr][ks * 32 + lg * 8];
#pragma unroll
    for (int mt = 0; mt < 4; ++mt) {
      int c = w * 64 + mt * 16 + lr;
      bf16x8 af = load_bf8(Wv + (size_t)c * NC + ks * 32 + lg * 8);
      accP[mt] = __builtin_amdgcn_mfma_f32_16x16x32_bf16(af, b0, accP[mt], 0, 0, 0);
    }
  }
  float qs = s.shQsum[lr];
#pragma unroll
  for (int mt = 0; mt < 4; ++mt) {
    float hacc[4];
#pragma unroll
    for (int r = 0; r < 4; ++r) {
      int c = w * 64 + mt * 16 + lg * 4 + r;
      float val = accP[mt][r] + bv[c] * qs;
      P[((size_t)b * NC + c) * NK + jg * 16 + lr] = (__bf16)val;
      hacc[r] = val * bkj;
    }
#pragma unroll
    for (int r = 0; r < 4; ++r) {
      float v = hacc[r];
      v += __shfl_xor(v, 1); v += __shfl_xor(v, 2);
      v += __shfl_xor(v, 4); v += __shfl_xor(v, 8);
      if (lr == 0)
        h2[((size_t)b * 2 + jg) * NC + w * 64 + mt * 16 + lg * 4 + r] = v;
    }
  }
}

// ---------------- phase 3: back (R7 exact) -----------------------------------
__device__ __forceinline__ void back_body(
    const float* __restrict__ x, const __bf16* __restrict__ Kt_t,
    const __bf16* __restrict__ P, const float* __restrict__ h2,
    const float* __restrict__ gamma, float* __restrict__ out, int bid, int t) {
  int b = bid >> 6, n0 = (bid & 63) * 64;
  int lane = t & 63, w = t >> 6, lr = lane & 15, lg = lane >> 4;

  bf16x8 af = *(const bf16x8*)&Kt_t[((size_t)b * NN + n0 + w * 16 + lr) * NK + lg * 8];
  const __bf16* Pb = P + (size_t)b * NC * NK;
  f32x4 acc[16];
#pragma unroll
  for (int ft = 0; ft < 16; ++ft) {
    bf16x8 bfr = *(const bf16x8*)&Pb[(size_t)(ft * 16 + lr) * NK + lg * 8];
    f32x4 z = {0.f, 0.f, 0.f, 0.f};
    acc[ft] = __builtin_amdgcn_mfma_f32_16x16x32_bf16(af, bfr, z, 0, 0, 0);
  }
  float g = gamma[0];
  const float* h0 = h2 + (size_t)b * 2 * NC;
#pragma unroll
  for (int ft = 0; ft < 16; ++ft) {
    int c = ft * 16 + lr;
    float hc = h0[c] + h0[NC + c];
    size_t idx = ((size_t)b * NC + c) * NN + n0 + w * 16 + lg * 4;
    f32x4 xv = *(const f32x4*)&x[idx];
    f32x4 o;
#pragma unroll
    for (int r = 0; r < 4; ++r) o[r] = g * (acc[ft][r] + hc) + xv[r];
    *(f32x4*)&out[idx] = o;
  }
}

// ---------------- fused cooperative kernel -----------------------------------
__global__ __launch_bounds__(256, 2) void k_fused(
    const float* __restrict__ x, const float* __restrict__ Wq,
    const float* __restrict__ bq, const float* __restrict__ Wk,
    const float* __restrict__ Wv, const float* __restrict__ bv,
    const float* __restrict__ bk, const float* __restrict__ gamma,
    __bf16* __restrict__ Tpart, __bf16* __restrict__ Kt_t,
    float* __restrict__ qsp, __bf16* __restrict__ P,
    float* __restrict__ h2, float* __restrict__ out) {
  __shared__ SmemU smem;
  cg::grid_group grid = cg::this_grid();
  int bid = blockIdx.x, t = threadIdx.x;
  front_body(smem.f, x, Wq, bq, Wk, Tpart, Kt_t, qsp, bid, t);
  grid.sync();
  if (bid < NB * 8) reduce_body(Tpart, bid, t);
  grid.sync();
  if (bid < NB * 2) pgemm_body(smem.p, Tpart, qsp, Wv, bv, bk, P, h2, bid, t);
  grid.sync();
  back_body(x, Kt_t, P, h2, gamma, out, bid, t);
}

// ---------------- standalone fallbacks (R7 path) -----------------------------
__global__ __launch_bounds__(256) void k_front(
    const float* __restrict__ x, const float* __restrict__ Wq,
    const float* __restrict__ bq, const float* __restrict__ Wk,
    __bf16* __restrict__ Tpart, __bf16* __restrict__ Kt_t,
    float* __restrict__ qsp) {
  __shared__ SmemFront s;
  front_body(s, x, Wq, bq, Wk, Tpart, Kt_t, qsp, blockIdx.x, threadIdx.x);
}
__global__ __launch_bounds__(256) void k_reduce(__bf16* __restrict__ Tpart) {
  reduce_body(Tpart, blockIdx.x, threadIdx.x);
}
__global__ __launch_bounds__(256) void k_pgemm(
    const __bf16* __restrict__ T, const float* __restrict__ qsp,
    const float* __restrict__ Wv, const float* __restrict__ bv,
    const float* __restrict__ bk, __bf16* __restrict__ P,
    float* __restrict__ h2) {
  __shared__ SmemP s;
  pgemm_body(s, T, qsp, Wv, bv, bk, P, h2, blockIdx.x, threadIdx.x);
}
__global__ __launch_bounds__(256) void k_back(
    const float* __restrict__ x, const __bf16* __restrict__ Kt_t,
    const __bf16* __restrict__ P, const float* __restrict__ h2,
    const float* __restrict__ gamma, float* __restrict__ out) {
  back_body(x, Kt_t, P, h2, gamma, out, blockIdx.x, threadIdx.x);
}

extern "C" void kernel_launch(void* const* d_in, const int* in_sizes, int n_in,
                              void* d_out, int out_size, void* d_ws, size_t ws_size,
                              hipStream_t stream) {
  (void)in_sizes; (void)n_in; (void)out_size; (void)ws_size;
  const float* x     = (const float*)d_in[0];
  const float* Wk    = (const float*)d_in[1];
  const float* bk    = (const float*)d_in[2];
  const float* Wq    = (const float*)d_in[3];
  const float* bq    = (const float*)d_in[4];
  const float* Wv    = (const float*)d_in[5];
  const float* bv    = (const float*)d_in[6];
  const float* gamma = (const float*)d_in[7];
  float* out = (float*)d_out;

  char* wsb = (char*)d_ws;
  const size_t tpB = (size_t)NCHUNK * NB * NC * NK * 2;  // 8 MB
  const size_t ktB = (size_t)NB * NN * NK * 2;           // 2 MB
  const size_t qsB = (size_t)NCHUNK * NB * NK * 4;       // 64 KB
  const size_t pB  = (size_t)NB * NC * NK * 2;           // 128 KB
  __bf16* Tpart = (__bf16*)wsb;
  __bf16* Kt_t  = (__bf16*)(wsb + tpB);
  float*  qsp   = (float*)(wsb + tpB + ktB);
  __bf16* P     = (__bf16*)(wsb + tpB + ktB + qsB);
  float*  h2    = (float*)(wsb + tpB + ktB + qsB + pB);

  void* args[] = {(void*)&x,  (void*)&Wq, (void*)&bq, (void*)&Wk,
                  (void*)&Wv, (void*)&bv, (void*)&bk, (void*)&gamma,
                  (void*)&Tpart, (void*)&Kt_t, (void*)&qsp, (void*)&P,
                  (void*)&h2, (void*)&out};
  hipError_t e = hipLaunchCooperativeKernel(
      (const void*)k_fused, dim3(NB * NCHUNK), dim3(256), args, 0, stream);
  if (e != hipSuccess) {
    // fallback: proven R7 4-dispatch path
    k_front<<<NB * NCHUNK, 256, 0, stream>>>(x, Wq, bq, Wk, Tpart, Kt_t, qsp);
    k_reduce<<<NB * 8, 256, 0, stream>>>(Tpart);
    k_pgemm<<<NB * 2, 256, 0, stream>>>(Tpart, qsp, Wv, bv, bk, P, h2);
    k_back<<<NB * 64, 256, 0, stream>>>(x, Kt_t, P, h2, gamma, out);
  }
}

// Round 11
// 54.223 us; speedup vs baseline: 4.1321x; 4.1321x over previous
//
#include <hip/hip_runtime.h>

// SelfAttention2d, B=8 C=256 H=W=64 (N=4096), Ck=32, softmax dead code.
// out = gamma * (v q^T k) + x, reassociated:
//   Qt = X^T Wq^T + 1 bq^T      (N x 32, per-tile, LDS only)
//   Kt_t = X^T Wk^T             (N x 32, bf16, ws; bk folded into h)
//   T  = X Qt                   (256 x 32) n-chunked partials -> ws
//   qsum = Qt^T 1               (32)
//   P  = Wv T + bv qsum^T       (256 x 32), h = P bk
//   out = gamma * (P Kt + h 1^T) + x
// R11: front/back = R7-exact (proven 52.2; R10's cooperative grid.sync cost
// ~160us -> reverted). reduce+pgemm merged into ONE 64-block k_mid: each
// block reduces its (b, 4-j slice) across 64 chunks (full k-range for those
// columns) then computes P[:,4j] = Wv*T + bias and an h-partial. 3 dispatches.

constexpr int NB = 8;
constexpr int NC = 256;
constexpr int NK = 32;     // C/8
constexpr int NN = 4096;   // H*W
constexpr int NCHUNK = 64; // front n-chunks (64 n each)

typedef float  f32x4  __attribute__((ext_vector_type(4)));
typedef __bf16 bf16x4 __attribute__((ext_vector_type(4)));
typedef __bf16 bf16x8 __attribute__((ext_vector_type(8)));

__device__ __forceinline__ bf16x8 load_bf8(const float* __restrict__ p) {
  f32x4 a = *(const f32x4*)p;
  f32x4 b = *(const f32x4*)(p + 4);
  bf16x8 r;
  r[0] = (__bf16)a[0]; r[1] = (__bf16)a[1]; r[2] = (__bf16)a[2]; r[3] = (__bf16)a[3];
  r[4] = (__bf16)b[0]; r[5] = (__bf16)b[1]; r[6] = (__bf16)b[2]; r[7] = (__bf16)b[3];
  return r;
}

// ---------------- front: Qt/Kt for one 64-n subtile; T partial; qsum partial --
// grid = NB*64 (512 blocks, 2/CU), 256 threads (4 waves).  [R7 exact]
__global__ __launch_bounds__(256) void k_front(
    const float* __restrict__ x, const float* __restrict__ Wq,
    const float* __restrict__ bq, const float* __restrict__ Wk,
    __bf16* __restrict__ Tpart, __bf16* __restrict__ Kt_t,
    float* __restrict__ qsum_part) {
  __shared__ __bf16 ldsT[64 * 264];   // x-subtile transposed [n][c], XOR-swizzled
  __shared__ __bf16 ldsW[2][32][264]; // Wq, Wk bf16 [j][c]
  __shared__ __bf16 ldsQt[32][72];    // Q^T subtile [j][n]
  __shared__ __bf16 ldsKt[32][72];    // K^T subtile [j][n]
  __shared__ float  ldsQs[4][32];
  int bid = blockIdx.x;
  int b = bid >> 6, chunk = bid & 63;
  int nsub = chunk * 64;
  int t = threadIdx.x;
  int lane = t & 63, w = t >> 6, lr = lane & 15, lg = lane >> 4;
  const float* xb = x + (size_t)b * NC * NN;
  float bq0 = bq[lr], bq1 = bq[16 + lr];

  {  // weight stage: Wq/Wk f32[32][256] -> ldsW bf16, once per block
    int m = t >> 7, tid = t & 127;
    int j = tid >> 2, c0 = (tid & 3) * 64;
    const float* Ws = m ? Wk : Wq;
#pragma unroll
    for (int i = 0; i < 16; ++i) {
      f32x4 v = *(const f32x4*)(Ws + j * NC + c0 + i * 4);
      bf16x4 pk = {(__bf16)v[0], (__bf16)v[1], (__bf16)v[2], (__bf16)v[3]};
      *(bf16x4*)&ldsW[m][j][c0 + i * 4] = pk;
    }
  }
  {  // stage x[0:256][nsub:nsub+64] -> ldsT swizzled, fully coalesced reads
    int cg = t >> 4, ng = t & 15;
    int n0 = ng * 4;
    int swzEl = (ng & 7) << 3;
#pragma unroll
    for (int r = 0; r < 4; ++r) {
      int c0 = r * 64 + cg * 4;
      const float* src = xb + (size_t)c0 * NN + nsub + n0;
      f32x4 L0 = *(const f32x4*)(src);
      f32x4 L1 = *(const f32x4*)(src + NN);
      f32x4 L2 = *(const f32x4*)(src + 2 * NN);
      f32x4 L3 = *(const f32x4*)(src + 3 * NN);
#pragma unroll
      for (int jj = 0; jj < 4; ++jj) {
        bf16x4 pk = {(__bf16)L0[jj], (__bf16)L1[jj], (__bf16)L2[jj], (__bf16)L3[jj]};
        *(bf16x4*)&ldsT[(n0 + jj) * 264 + (c0 ^ swzEl)] = pk;
      }
    }
  }
  __syncthreads();
  // Qt(64x32) and Kt(64x32): all-LDS operands; A-frag reads use the swizzle
  f32x4 aq[2] = {}, ak[2] = {};
  {
    int n = w * 16 + lr;
    int swzA = ((n >> 2) & 7) << 3;
    int rowA = n * 264;
#pragma unroll
    for (int ks = 0; ks < 8; ++ks) {
      bf16x8 af = *(const bf16x8*)&ldsT[rowA + ((ks * 32 + lg * 8) ^ swzA)];
      bf16x8 q0 = *(const bf16x8*)&ldsW[0][lr][ks * 32 + lg * 8];
      bf16x8 q1 = *(const bf16x8*)&ldsW[0][16 + lr][ks * 32 + lg * 8];
      bf16x8 k0 = *(const bf16x8*)&ldsW[1][lr][ks * 32 + lg * 8];
      bf16x8 k1 = *(const bf16x8*)&ldsW[1][16 + lr][ks * 32 + lg * 8];
      aq[0] = __builtin_amdgcn_mfma_f32_16x16x32_bf16(af, q0, aq[0], 0, 0, 0);
      aq[1] = __builtin_amdgcn_mfma_f32_16x16x32_bf16(af, q1, aq[1], 0, 0, 0);
      ak[0] = __builtin_amdgcn_mfma_f32_16x16x32_bf16(af, k0, ak[0], 0, 0, 0);
      ak[1] = __builtin_amdgcn_mfma_f32_16x16x32_bf16(af, k1, ak[1], 0, 0, 0);
    }
  }
  float qs0, qs1;
#pragma unroll
  for (int r = 0; r < 4; ++r) { aq[0][r] += bq0; aq[1][r] += bq1; }
  qs0 = aq[0][0] + aq[0][1] + aq[0][2] + aq[0][3];
  qs1 = aq[1][0] + aq[1][1] + aq[1][2] + aq[1][3];
  {  // Qt / Kt -> LDS [j][n]
    bf16x4 p0 = {(__bf16)aq[0][0], (__bf16)aq[0][1], (__bf16)aq[0][2], (__bf16)aq[0][3]};
    bf16x4 p1 = {(__bf16)aq[1][0], (__bf16)aq[1][1], (__bf16)aq[1][2], (__bf16)aq[1][3]};
    *(bf16x4*)&ldsQt[lr][w * 16 + lg * 4] = p0;
    *(bf16x4*)&ldsQt[16 + lr][w * 16 + lg * 4] = p1;
    bf16x4 k0p = {(__bf16)ak[0][0], (__bf16)ak[0][1], (__bf16)ak[0][2], (__bf16)ak[0][3]};
    bf16x4 k1p = {(__bf16)ak[1][0], (__bf16)ak[1][1], (__bf16)ak[1][2], (__bf16)ak[1][3]};
    *(bf16x4*)&ldsKt[lr][w * 16 + lg * 4] = k0p;
    *(bf16x4*)&ldsKt[16 + lr][w * 16 + lg * 4] = k1p;
  }
  __syncthreads();
  {  // Kt coalesced store: thread t covers (nloc = t>>2, 8 j) -> 16 B store
    int nloc = t >> 2, j0 = (t & 3) * 8;
    bf16x8 pk;
#pragma unroll
    for (int i = 0; i < 8; ++i) pk[i] = ldsKt[j0 + i][nloc];
    *(bf16x8*)&Kt_t[((size_t)b * NN + nsub + nloc) * NK + j0] = pk;
  }
  // T(256x32) = X Qt : A = x rows from global (L1/L2-hot), B = ldsQt rows
  f32x4 accT[4][2] = {};
#pragma unroll
  for (int ks2 = 0; ks2 < 2; ++ks2) {
    bf16x8 bf0 = *(const bf16x8*)&ldsQt[lr][ks2 * 32 + lg * 8];
    bf16x8 bf1 = *(const bf16x8*)&ldsQt[16 + lr][ks2 * 32 + lg * 8];
#pragma unroll
    for (int mt = 0; mt < 4; ++mt) {
      int c = w * 64 + mt * 16 + lr;
      bf16x8 af = load_bf8(xb + (size_t)c * NN + nsub + ks2 * 32 + lg * 8);
      accT[mt][0] = __builtin_amdgcn_mfma_f32_16x16x32_bf16(af, bf0, accT[mt][0], 0, 0, 0);
      accT[mt][1] = __builtin_amdgcn_mfma_f32_16x16x32_bf16(af, bf1, accT[mt][1], 0, 0, 0);
    }
  }
  // qsum partial
  qs0 += __shfl_xor(qs0, 16); qs0 += __shfl_xor(qs0, 32);
  qs1 += __shfl_xor(qs1, 16); qs1 += __shfl_xor(qs1, 32);
  if (lane < 16) { ldsQs[w][lane] = qs0; ldsQs[w][16 + lane] = qs1; }
  __syncthreads();
  if (t < 32)
    qsum_part[(size_t)(chunk * NB + b) * NK + t] =
        ldsQs[0][t] + ldsQs[1][t] + ldsQs[2][t] + ldsQs[3][t];
  // Tpart[chunk][b][j][c] bf16
  __bf16* Tp = Tpart + (size_t)(chunk * NB + b) * NC * NK;
#pragma unroll
  for (int mt = 0; mt < 4; ++mt)
#pragma unroll
    for (int jf = 0; jf < 2; ++jf) {
      bf16x4 pk = {(__bf16)accT[mt][jf][0], (__bf16)accT[mt][jf][1],
                   (__bf16)accT[mt][jf][2], (__bf16)accT[mt][jf][3]};
      *(bf16x4*)&Tp[(jf * 16 + lr) * NC + w * 64 + mt * 16 + lg * 4] = pk;
    }
}

// ---------------- mid: reduce (b, 4-j slice) + P[:,4j] GEMM + h partial -------
// grid = NB*8 (64 blocks), 256 threads. Block owns columns j = js*4..js*4+3.
// After reducing T[:, 4j] over all 64 chunks (full k-range c'=0..255), the
// block computes P[:, 4j] = Wv*T + bv qsum^T and h8[js] = P[:,4j]*bk[4j].
__global__ __launch_bounds__(256) void k_mid(
    const __bf16* __restrict__ Tpart, const float* __restrict__ qsum_part,
    const float* __restrict__ Wv, const float* __restrict__ bv,
    const float* __restrict__ bk, __bf16* __restrict__ P,
    float* __restrict__ h8) {
  __shared__ __bf16 shT[16][264];  // rows 0-3 = T^T[j][c']; rows 4-15 unused
  __shared__ float shQ[4];
  int bid = blockIdx.x;
  int b = bid >> 3, js = bid & 7;
  int t = threadIdx.x;
  if (t < 4) {
    float s = 0.f;
#pragma unroll 8
    for (int ch = 0; ch < NCHUNK; ++ch)
      s += qsum_part[(size_t)(ch * NB + b) * NK + js * 4 + t];
    shQ[t] = s;
  }
  if (t < 64 && t >= 4) {  // zero unused shT rows region cheaply (rows 4-15)
    // each of 60 threads zeros 53 elements; just let 256 threads do it below
  }
  {  // zero rows 4..15 so garbage can't alias (t covers 12*264=3168 elems)
    for (int i = t; i < 12 * 264; i += 256) shT[4 + i / 264][i % 264] = (__bf16)0.f;
  }
  {  // phase A: reduce own 4-j slice across 64 chunks (wide, coalesced)
    int jo = t >> 6, c0 = (t & 63) * 4;
    const size_t chstride = (size_t)NB * NK * NC;
    size_t idx = ((size_t)b * NK + js * 4 + jo) * NC + c0;
    float acc[4] = {};
#pragma unroll 8
    for (int ch = 0; ch < NCHUNK; ++ch) {
      bf16x4 v = *(const bf16x4*)&Tpart[ch * chstride + idx];
#pragma unroll
      for (int i = 0; i < 4; ++i) acc[i] += (float)v[i];
    }
    bf16x4 o = {(__bf16)acc[0], (__bf16)acc[1], (__bf16)acc[2], (__bf16)acc[3]};
    *(bf16x4*)&shT[jo][c0] = o;
  }
  __syncthreads();
  // phase B: P[c][4j] = Wv T + bv qsum^T ; h8 partial = P bk-slice
  int lane = t & 63, w = t >> 6, lr = lane & 15, lg = lane >> 4;
  float bkj = bk[js * 4 + (lr & 3)];
  float qs = shQ[lr & 3];
  f32x4 accP[4] = {};
#pragma unroll
  for (int ks = 0; ks < 8; ++ks) {
    bf16x8 b0 = *(const bf16x8*)&shT[lr][ks * 32 + lg * 8];
#pragma unroll
    for (int mt = 0; mt < 4; ++mt) {
      int c = w * 64 + mt * 16 + lr;
      bf16x8 af = load_bf8(Wv + (size_t)c * NC + ks * 32 + lg * 8);
      accP[mt] = __builtin_amdgcn_mfma_f32_16x16x32_bf16(af, b0, accP[mt], 0, 0, 0);
    }
  }
  // D layout: col j' = lr (valid lr<4), row c = w*64+mt*16+lg*4+r
#pragma unroll
  for (int mt = 0; mt < 4; ++mt) {
    float hacc[4];
#pragma unroll
    for (int r = 0; r < 4; ++r) {
      int c = w * 64 + mt * 16 + lg * 4 + r;
      float val = accP[mt][r] + bv[c] * qs;
      if (lr < 4) P[((size_t)b * NC + c) * NK + js * 4 + lr] = (__bf16)val;
      hacc[r] = val * bkj;
    }
#pragma unroll
    for (int r = 0; r < 4; ++r) {
      float v = hacc[r];
      v += __shfl_xor(v, 1); v += __shfl_xor(v, 2);
      if (lr == 0) {
        int c = w * 64 + mt * 16 + lg * 4 + r;
        h8[((size_t)b * NC + c) * 8 + js] = v;
      }
    }
  }
}

// ---------------- back: out = gamma*(P Kt + h 1^T) + x -----------------------
// D[n][c] orientation: A = Kt_t[n][j] (global, contiguous), B = P[c][j] rows.
// grid = NB*64 (n-tiles of 64), 256 threads (4 waves), NO LDS, NO syncs. [R7]
__global__ __launch_bounds__(256) void k_back(
    const float* __restrict__ x, const __bf16* __restrict__ Kt_t,
    const __bf16* __restrict__ P, const float* __restrict__ h8,
    const float* __restrict__ gamma, float* __restrict__ out) {
  int bid = blockIdx.x;
  int b = bid >> 6, n0 = (bid & 63) * 64;
  int t = threadIdx.x;
  int lane = t & 63, w = t >> 6, lr = lane & 15, lg = lane >> 4;

  bf16x8 af = *(const bf16x8*)&Kt_t[((size_t)b * NN + n0 + w * 16 + lr) * NK + lg * 8];
  const __bf16* Pb = P + (size_t)b * NC * NK;
  f32x4 acc[16];
#pragma unroll
  for (int ft = 0; ft < 16; ++ft) {
    bf16x8 bfr = *(const bf16x8*)&Pb[(size_t)(ft * 16 + lr) * NK + lg * 8];
    f32x4 z = {0.f, 0.f, 0.f, 0.f};
    acc[ft] = __builtin_amdgcn_mfma_f32_16x16x32_bf16(af, bfr, z, 0, 0, 0);
  }
  float g = gamma[0];
  const float* hb = h8 + (size_t)b * NC * 8;
#pragma unroll
  for (int ft = 0; ft < 16; ++ft) {
    int c = ft * 16 + lr;
    f32x4 hv0 = *(const f32x4*)&hb[c * 8];
    f32x4 hv1 = *(const f32x4*)&hb[c * 8 + 4];
    float hc = (hv0[0] + hv0[1] + hv0[2] + hv0[3]) +
               (hv1[0] + hv1[1] + hv1[2] + hv1[3]);
    size_t idx = ((size_t)b * NC + c) * NN + n0 + w * 16 + lg * 4;
    f32x4 xv = *(const f32x4*)&x[idx];
    f32x4 o;
#pragma unroll
    for (int r = 0; r < 4; ++r) o[r] = g * (acc[ft][r] + hc) + xv[r];
    *(f32x4*)&out[idx] = o;
  }
}

extern "C" void kernel_launch(void* const* d_in, const int* in_sizes, int n_in,
                              void* d_out, int out_size, void* d_ws, size_t ws_size,
                              hipStream_t stream) {
  (void)in_sizes; (void)n_in; (void)out_size; (void)ws_size;
  const float* x     = (const float*)d_in[0];
  const float* Wk    = (const float*)d_in[1];
  const float* bk    = (const float*)d_in[2];
  const float* Wq    = (const float*)d_in[3];
  const float* bq    = (const float*)d_in[4];
  const float* Wv    = (const float*)d_in[5];
  const float* bv    = (const float*)d_in[6];
  const float* gamma = (const float*)d_in[7];
  float* out = (float*)d_out;

  char* wsb = (char*)d_ws;
  const size_t tpB = (size_t)NCHUNK * NB * NC * NK * 2;  // 8 MB
  const size_t ktB = (size_t)NB * NN * NK * 2;           // 2 MB
  const size_t qsB = (size_t)NCHUNK * NB * NK * 4;       // 64 KB
  const size_t pB  = (size_t)NB * NC * NK * 2;           // 128 KB
  __bf16* Tpart = (__bf16*)wsb;
  __bf16* Kt_t  = (__bf16*)(wsb + tpB);
  float*  qsp   = (float*)(wsb + tpB + ktB);
  __bf16* P     = (__bf16*)(wsb + tpB + ktB + qsB);
  float*  h8    = (float*)(wsb + tpB + ktB + qsB + pB);  // NB*NC*8 f32 = 64 KB

  k_front<<<NB * NCHUNK, 256, 0, stream>>>(x, Wq, bq, Wk, Tpart, Kt_t, qsp);
  k_mid<<<NB * 8, 256, 0, stream>>>(Tpart, qsp, Wv, bv, bk, P, h8);
  k_back<<<NB * 64, 256, 0, stream>>>(x, Kt_t, P, h8, gamma, out);
}